// Round 1
// baseline (169.271 us; speedup 1.0000x reference)
//
#include <hip/hip_runtime.h>
#include <hip/hip_bf16.h>

typedef __attribute__((ext_vector_type(8))) short short8;
typedef __attribute__((ext_vector_type(8))) unsigned short ushort8;
typedef __attribute__((ext_vector_type(4))) float f32x4;

#define LIN  8192
#define L3V  8189
#define NOUT 128
#define KP   8192
#define BM   64
#define BK   128
#define NT   (KP / BK)       // 64 chunks
#define PITCH (BK + 8)       // 136 shorts/row -> rows advance 4 banks, ~2-way (free)

// round-to-nearest-even fp32 -> bf16 (values are finite here)
static __device__ __forceinline__ unsigned short f2bf(float f) {
    union { float f; unsigned u; } c; c.f = f;
    unsigned r = c.u + 0x7FFFu + ((c.u >> 16) & 1u);
    return (unsigned short)(r >> 16);
}

// W [128][8189] fp32 -> Wb [128][8192] bf16, zero-padded tail
__global__ void wprep(const float* __restrict__ W, unsigned short* __restrict__ Wb) {
    int idx = blockIdx.x * 256 + threadIdx.x;     // 0 .. 128*8192-1
    int n = idx >> 13;
    int k = idx & (KP - 1);
    float v = (k < L3V) ? W[(size_t)n * L3V + k] : 0.0f;
    Wb[idx] = f2bf(v);
}

__global__ __launch_bounds__(512, 2) void fused(
    const float* __restrict__ x,
    const float* __restrict__ w1, const float* __restrict__ b1,
    const float* __restrict__ w2, const float* __restrict__ b2,
    const float* __restrict__ w3, const float* __restrict__ b3,
    const unsigned short* __restrict__ Wb,
    const float* __restrict__ bias,
    float* __restrict__ out)
{
    __shared__ unsigned short hA[2][BM * PITCH];      // 2 x 17408 B
    __shared__ unsigned short wA[2][NOUT * PITCH];    // 2 x 34816 B  (total 104448 B)

    const int tid  = threadIdx.x;
    const int row0 = blockIdx.x * BM;

    const float w10 = w1[0], w11 = w1[1], cb1 = b1[0];
    const float w20 = w2[0], w21 = w2[1], cb2 = b2[0];
    const float w30 = w3[0], w31 = w3[1], cb3 = b3[0];

    // staging mapping: 64 rows x 8 segments of 16 h-values
    const int srow = tid >> 3;          // 0..63
    const int scol = (tid & 7) * 16;    // 0,16,...,112
    const float* xrow = x + (size_t)(row0 + srow) * LIN;

    // W staging mapping: 128 rows x 4 quarters of 32 cols
    const int wn = tid >> 2;            // 0..127
    const int wq = tid & 3;             // 0..3

    // mfma mapping: 8 waves = 4 row-groups x 2 col-groups; wave = 16 rows x 64 cols
    const int lane = tid & 63;
    const int wid  = tid >> 6;
    const int wr   = wid >> 1;          // 0..3
    const int wc   = wid & 1;           // 0..1
    const int l15  = lane & 15;
    const int koff = (lane >> 4) * 8;
    const int arow_off = (wr * 16 + l15) * PITCH + koff;

    f32x4 acc[4];
    #pragma unroll
    for (int f = 0; f < 4; ++f) acc[f] = (f32x4){0.f, 0.f, 0.f, 0.f};

    auto stage = [&](int t, int s) {
        const int k0 = t * BK;
        const int gk = k0 + scol;
        // x[gk .. gk+19] (need 19 for 16 h3 outputs; load 20 for float4s)
        float xv[20];
        if (gk + 20 <= LIN) {
            #pragma unroll
            for (int q = 0; q < 5; ++q) {
                const float4 v = *reinterpret_cast<const float4*>(xrow + gk + q * 4);
                xv[q*4+0] = v.x; xv[q*4+1] = v.y; xv[q*4+2] = v.z; xv[q*4+3] = v.w;
            }
        } else {
            #pragma unroll
            for (int j = 0; j < 20; ++j)
                xv[j] = (gk + j < LIN) ? xrow[gk + j] : 0.0f;
        }
        float h1[18];
        #pragma unroll
        for (int j = 0; j < 18; ++j)
            h1[j] = fmaxf(fmaf(w10, xv[j], fmaf(w11, xv[j+1], cb1)), 0.0f);
        float h2[17];
        #pragma unroll
        for (int j = 0; j < 17; ++j)
            h2[j] = fmaxf(fmaf(w20, h1[j], fmaf(w21, h1[j+1], cb2)), 0.0f);
        ushort8 hp[2];
        #pragma unroll
        for (int j = 0; j < 16; ++j) {
            float h3 = fmaxf(fmaf(w30, h2[j], fmaf(w31, h2[j+1], cb3)), 0.0f);
            unsigned short u = (gk + j < L3V) ? f2bf(h3) : (unsigned short)0;
            hp[j >> 3][j & 7] = u;
        }
        ushort8* hd = reinterpret_cast<ushort8*>(&hA[s][srow * PITCH + scol]);
        hd[0] = hp[0];
        hd[1] = hp[1];
        // W chunk: 128 x 128 bf16
        const ushort8* wsrc = reinterpret_cast<const ushort8*>(Wb + (size_t)wn * KP + k0 + wq * 32);
        ushort8* wdst = reinterpret_cast<ushort8*>(&wA[s][wn * PITCH + wq * 32]);
        #pragma unroll
        for (int i = 0; i < 4; ++i) wdst[i] = wsrc[i];
    };

    stage(0, 0);
    int sel = 0;
    for (int t = 0; t < NT; ++t) {
        __syncthreads();                       // buf[sel] writes complete everywhere
        if (t + 1 < NT) stage(t + 1, sel ^ 1); // prefetch next chunk into other buffer
        const unsigned short* hB = hA[sel];
        const unsigned short* wB = wA[sel];
        #pragma unroll
        for (int kk = 0; kk < BK; kk += 32) {
            const short8 af = *reinterpret_cast<const short8*>(&hB[arow_off + kk]);
            #pragma unroll
            for (int f = 0; f < 4; ++f) {
                const int bn = wc * 64 + f * 16 + l15;
                const short8 bf = *reinterpret_cast<const short8*>(&wB[bn * PITCH + kk + koff]);
                acc[f] = __builtin_amdgcn_mfma_f32_16x16x32_bf16(af, bf, acc[f], 0, 0, 0);
            }
        }
        sel ^= 1;
    }

    // epilogue: C[m][n]: col = lane&15, row = (lane>>4)*4 + j   [m89 layout]
    #pragma unroll
    for (int f = 0; f < 4; ++f) {
        const int col = wc * 64 + f * 16 + l15;
        const float bv = bias[col];
        #pragma unroll
        for (int j = 0; j < 4; ++j) {
            const int grow = row0 + wr * 16 + (lane >> 4) * 4 + j;
            out[(size_t)grow * NOUT + col] = acc[f][j] + bv;
        }
    }
}

extern "C" void kernel_launch(void* const* d_in, const int* in_sizes, int n_in,
                              void* d_out, int out_size, void* d_ws, size_t ws_size,
                              hipStream_t stream) {
    const float* x  = (const float*)d_in[0];
    const float* w1 = (const float*)d_in[1];
    const float* b1 = (const float*)d_in[2];
    const float* w2 = (const float*)d_in[3];
    const float* b2 = (const float*)d_in[4];
    const float* w3 = (const float*)d_in[5];
    const float* b3 = (const float*)d_in[6];
    const float* W  = (const float*)d_in[7];
    const float* b  = (const float*)d_in[8];
    float* out = (float*)d_out;
    unsigned short* Wb = (unsigned short*)d_ws;   // 128*8192 bf16 = 2 MiB

    wprep<<<dim3((NOUT * KP) / 256), dim3(256), 0, stream>>>(W, Wb);
    fused<<<dim3(16384 / BM), dim3(512), 0, stream>>>(
        x, w1, b1, w2, b2, w3, b3, Wb, b, out);
}

// Round 2
// 142.927 us; speedup vs baseline: 1.1843x; 1.1843x over previous
//
#include <hip/hip_runtime.h>
#include <hip/hip_bf16.h>

typedef __attribute__((ext_vector_type(8))) short short8;
typedef __attribute__((ext_vector_type(8))) unsigned short ushort8;
typedef __attribute__((ext_vector_type(4))) float f32x4;

#define LIN  8192
#define L3V  8189
#define NOUT 128
#define KP   8192
#define BM   64
#define BK   128
#define NT   (KP / BK)       // 64 chunks
#define PITCH (BK + 8)       // 136 shorts/row -> rows advance 4 banks, ~2-way (free)

// round-to-nearest-even fp32 -> bf16 (values are finite here)
static __device__ __forceinline__ unsigned short f2bf(float f) {
    union { float f; unsigned u; } c; c.f = f;
    unsigned r = c.u + 0x7FFFu + ((c.u >> 16) & 1u);
    return (unsigned short)(r >> 16);
}

// W [128][8189] fp32 -> Wb [128][8192] bf16, zero-padded tail
__global__ void wprep(const float* __restrict__ W, unsigned short* __restrict__ Wb) {
    int idx = blockIdx.x * 256 + threadIdx.x;     // 0 .. 128*8192-1
    int n = idx >> 13;
    int k = idx & (KP - 1);
    float v = (k < L3V) ? W[(size_t)n * L3V + k] : 0.0f;
    Wb[idx] = f2bf(v);
}

__global__ __launch_bounds__(512, 2) void fused(
    const float* __restrict__ x,
    const float* __restrict__ w1, const float* __restrict__ b1,
    const float* __restrict__ w2, const float* __restrict__ b2,
    const float* __restrict__ w3, const float* __restrict__ b3,
    const unsigned short* __restrict__ Wb,
    const float* __restrict__ bias,
    float* __restrict__ out)
{
    __shared__ unsigned short hA[2][BM * PITCH];      // 2 x 17408 B
    __shared__ unsigned short wA[2][NOUT * PITCH];    // 2 x 34816 B  (total 104448 B)

    const int tid  = threadIdx.x;
    const int row0 = blockIdx.x * BM;

    const float w10 = w1[0], w11 = w1[1], cb1 = b1[0];
    const float w20 = w2[0], w21 = w2[1], cb2 = b2[0];
    const float w30 = w3[0], w31 = w3[1], cb3 = b3[0];

    // staging mapping: 64 rows x 8 segments of 16 h-values
    const int srow = tid >> 3;          // 0..63
    const int scol = (tid & 7) * 16;    // 0,16,...,112
    const float* xrow = x + (size_t)(row0 + srow) * LIN;

    // W staging mapping: 128 rows x 4 quarters of 32 cols
    const int wn = tid >> 2;            // 0..127
    const int wq = tid & 3;             // 0..3
    const unsigned short* wrow = Wb + (size_t)wn * KP + wq * 32;

    // mfma mapping: 8 waves = 4 row-groups x 2 col-groups; wave = 16 rows x 64 cols
    const int lane = tid & 63;
    const int wid  = tid >> 6;
    const int wr   = wid >> 1;          // 0..3
    const int wc   = wid & 1;           // 0..1
    const int l15  = lane & 15;
    const int koff = (lane >> 4) * 8;
    const int arow_off = (wr * 16 + l15) * PITCH + koff;

    f32x4 acc[4];
    #pragma unroll
    for (int f = 0; f < 4; ++f) acc[f] = (f32x4){0.f, 0.f, 0.f, 0.f};

    // register staging state (T14: issue-early / conv+write-late)
    float   xv[20];
    ushort8 wv[4];

    auto stage_load = [&](int t) {
        const int gk = t * BK + scol;
        if (gk + 20 <= LIN) {                 // false only for t==NT-1 && scol==112
            #pragma unroll
            for (int q = 0; q < 5; ++q) {
                const float4 v = *reinterpret_cast<const float4*>(xrow + gk + q * 4);
                xv[q*4+0] = v.x; xv[q*4+1] = v.y; xv[q*4+2] = v.z; xv[q*4+3] = v.w;
            }
        } else {
            #pragma unroll
            for (int q = 0; q < 4; ++q) {     // gk+16 == LIN here, in bounds
                const float4 v = *reinterpret_cast<const float4*>(xrow + gk + q * 4);
                xv[q*4+0] = v.x; xv[q*4+1] = v.y; xv[q*4+2] = v.z; xv[q*4+3] = v.w;
            }
            xv[16] = 0.f; xv[17] = 0.f; xv[18] = 0.f; xv[19] = 0.f;
            // affected h3 indices are >= L3V and get zero-masked in stage_store
        }
        const ushort8* wsrc = reinterpret_cast<const ushort8*>(wrow + t * BK);
        #pragma unroll
        for (int i = 0; i < 4; ++i) wv[i] = wsrc[i];
    };

    auto stage_store = [&](int t, int s) {
        const int gk = t * BK + scol;
        float h1[18];
        #pragma unroll
        for (int j = 0; j < 18; ++j)
            h1[j] = fmaxf(fmaf(w10, xv[j], fmaf(w11, xv[j+1], cb1)), 0.0f);
        float h2[17];
        #pragma unroll
        for (int j = 0; j < 17; ++j)
            h2[j] = fmaxf(fmaf(w20, h1[j], fmaf(w21, h1[j+1], cb2)), 0.0f);
        ushort8 hp[2];
        #pragma unroll
        for (int j = 0; j < 16; ++j) {
            float h3 = fmaxf(fmaf(w30, h2[j], fmaf(w31, h2[j+1], cb3)), 0.0f);
            unsigned short u = (gk + j < L3V) ? f2bf(h3) : (unsigned short)0;
            hp[j >> 3][j & 7] = u;
        }
        ushort8* hd = reinterpret_cast<ushort8*>(&hA[s][srow * PITCH + scol]);
        hd[0] = hp[0];
        hd[1] = hp[1];
        ushort8* wdst = reinterpret_cast<ushort8*>(&wA[s][wn * PITCH + wq * 32]);
        #pragma unroll
        for (int i = 0; i < 4; ++i) wdst[i] = wv[i];
    };

    // prologue: fill buf0, start loads for chunk 1
    stage_load(0);
    stage_store(0, 0);
    stage_load(1);
    __syncthreads();

    int sel = 0;
    for (int t = 0; t < NT; ++t) {
        // MFMA on current buffer (regs for t+1 already in flight)
        const unsigned short* hB = hA[sel];
        const unsigned short* wB = wA[sel];
        #pragma unroll
        for (int kk = 0; kk < BK; kk += 32) {
            const short8 af = *reinterpret_cast<const short8*>(&hB[arow_off + kk]);
            #pragma unroll
            for (int f = 0; f < 4; ++f) {
                const int bn = wc * 64 + f * 16 + l15;
                const short8 bf = *reinterpret_cast<const short8*>(&wB[bn * PITCH + kk + koff]);
                acc[f] = __builtin_amdgcn_mfma_f32_16x16x32_bf16(af, bf, acc[f], 0, 0, 0);
            }
        }
        if (t + 1 < NT) stage_store(t + 1, sel ^ 1);  // consume regs -> LDS
        if (t + 2 < NT) stage_load(t + 2);            // refill regs, stay in flight
        __syncthreads();
        sel ^= 1;
    }

    // epilogue: C[m][n]: col = lane&15, row = (lane>>4)*4 + j   [m89 layout]
    #pragma unroll
    for (int f = 0; f < 4; ++f) {
        const int col = wc * 64 + f * 16 + l15;
        const float bv = bias[col];
        #pragma unroll
        for (int j = 0; j < 4; ++j) {
            const int grow = row0 + wr * 16 + (lane >> 4) * 4 + j;
            out[(size_t)grow * NOUT + col] = acc[f][j] + bv;
        }
    }
}

extern "C" void kernel_launch(void* const* d_in, const int* in_sizes, int n_in,
                              void* d_out, int out_size, void* d_ws, size_t ws_size,
                              hipStream_t stream) {
    const float* x  = (const float*)d_in[0];
    const float* w1 = (const float*)d_in[1];
    const float* b1 = (const float*)d_in[2];
    const float* w2 = (const float*)d_in[3];
    const float* b2 = (const float*)d_in[4];
    const float* w3 = (const float*)d_in[5];
    const float* b3 = (const float*)d_in[6];
    const float* W  = (const float*)d_in[7];
    const float* b  = (const float*)d_in[8];
    float* out = (float*)d_out;
    unsigned short* Wb = (unsigned short*)d_ws;   // 128*8192 bf16 = 2 MiB

    wprep<<<dim3((NOUT * KP) / 256), dim3(256), 0, stream>>>(W, Wb);
    fused<<<dim3(16384 / BM), dim3(512), 0, stream>>>(
        x, w1, b1, w2, b2, w3, b3, Wb, b, out);
}